// Round 12
// baseline (251.711 us; speedup 1.0000x reference)
//
#include <hip/hip_runtime.h>

// SinkhornOT — round 12: FUSED kernel = R7 proj (verbatim, proven 186us) +
// R2 register-cached solver (verbatim, fastest) reading C from LDS. Kills the
// C round-trip + solver launch; solver barrier-chains hide under co-resident
// blocks' MFMA phases (retirement-staggered rounds).
// B=2048, K=M=64, D=256, eps=0.05, 20 sinkhorn iters, 3 MESH iters.

typedef __attribute__((ext_vector_type(8))) short s16x8;
typedef __attribute__((ext_vector_type(4))) float f32x4;

#define OFF_T  2048
#define OFF_C  (2048 + 2048 * 4096)
#define OFF_TC (2048 + 2 * 2048 * 4096)

__device__ __forceinline__ unsigned short f2bf(float x) {  // RNE f32->bf16
  unsigned u = __builtin_bit_cast(unsigned, x);
  u += 0x7fffu + ((u >> 16) & 1u);
  return (unsigned short)(u >> 16);
}
__device__ __forceinline__ unsigned cvtpk(float lo, float hi) {
  unsigned r;
  asm("v_cvt_pk_bf16_f32 %0, %1, %2" : "=v"(r) : "v"(lo), "v"(hi));
  return r;
}

#define MFMA16(a, b, c) __builtin_amdgcn_mfma_f32_16x16x32_bf16((a), (b), (c), 0, 0, 0)

// Pack W (f32 [k][col]) into fragment-major bf16 (1KiB contiguous per frag:
// frag (cf=col>>4, ks=k>>5) at cf*4096+ks*512, lane=((k>>3)&3)*16+(col&15),
// byte ii=k&7). Serves as the swapped-GEMM A-operand.
__global__ void __launch_bounds__(256)
prep_w_kernel(const float* __restrict__ W1, const float* __restrict__ W2,
              short* __restrict__ W1p, short* __restrict__ W2p) {
  int i = blockIdx.x * 256 + threadIdx.x;   // 65536 threads exactly
  int k = i >> 8, col = i & 255;
  int p = (col >> 4) * 4096 + (k >> 5) * 512 +
          (((k >> 3) & 3) * 16 + (col & 15)) * 8 + (k & 7);
  W1p[p] = (short)f2bf(W1[i]);
  W2p[p] = (short)f2bf(W2[i]);
}

// K-loop, operand-swapped: acc[nf][rf] holds D[e][r]. A = packed W frag
// (depth-4 register ring), B = X/H row frag from LDS.
__device__ __forceinline__ void gemm_kloop(const short* __restrict__ wb,
                                           const char* sm, int abase0, int asw,
                                           int koff0, f32x4 (&acc)[4][8]) {
  s16x8 bw[4][4];
#pragma unroll
  for (int p = 0; p < 4; ++p)
#pragma unroll
    for (int nf = 0; nf < 4; ++nf)
      bw[p][nf] = *(const s16x8*)(wb + nf * 4096 + p * 512);
#pragma unroll
  for (int ks = 0; ks < 8; ++ks) {
    const int ko = (ks * 64 + koff0) ^ asw;
    s16x8 af[8];
#pragma unroll
    for (int rf = 0; rf < 8; ++rf)
      af[rf] = *(const s16x8*)(sm + rf * 8192 + abase0 + ko);
#pragma unroll
    for (int rf = 0; rf < 8; ++rf)
#pragma unroll
      for (int nf = 0; nf < 4; ++nf)
        acc[nf][rf] = MFMA16(bw[ks & 3][nf], af[rf], acc[nf][rf]);
    if (ks < 4) {
#pragma unroll
      for (int nf = 0; nf < 4; ++nf)
        bw[ks & 3][nf] = *(const s16x8*)(wb + nf * 4096 + (ks + 4) * 512);
    }
  }
}

// =============== Fused kernel: proj + cdist + Sinkhorn + MESH ===============
__global__ void __launch_bounds__(256, 2)
sinkhorn_fused(const float* __restrict__ slots_q, const float* __restrict__ slots_r,
               const short* __restrict__ W1p, const short* __restrict__ W2p,
               const float* __restrict__ b1, const float* __restrict__ b2,
               const float* __restrict__ mask_r, float* __restrict__ out) {
  // [128 rows][512 B] swizzled bf16 tile: X -> H -> P. Head reused as
  // norm-partials [4][128] f32 (post-qr), then as C/T tile [64][65] f32.
  __shared__ char smem[65536];
  float* nbuf  = (float*)smem;
  float* tile  = (float*)smem;                 // [64][65] f32 (16640 B)
  float* u_arr = (float*)(smem + 16640);       // 64 f32
  float* w_arr = u_arr + 64;                   // 64 f32
  float* red   = w_arr + 64;                   // 4 f32

  const int b    = blockIdx.x;
  const int tid  = threadIdx.x;
  const int wv   = tid >> 6;
  const int lane = tid & 63;
  const int l15  = lane & 15;
  const int lhi  = lane >> 4;

  // mask preload into register (w_arr LDS region is live tile data until qr done)
  float mr = 1.0f;
  if (tid < 64) mr = mask_r[(size_t)b * 64 + tid];

  // ---------- stage X: 16 loads in flight, then convert+write (x2) ----------
  {
    const float* sq = slots_q + (size_t)b * 16384;
    const float* sr = slots_r + (size_t)b * 16384;
#pragma unroll
    for (int half = 0; half < 2; ++half) {
      float4 tmp[16];
#pragma unroll
      for (int i = 0; i < 16; ++i) {
        int idx4 = tid + 256 * (half * 16 + i);
        tmp[i] = (half == 0) ? *(const float4*)(sq + idx4 * 4)
                             : *(const float4*)(sr + (idx4 - 4096) * 4);
      }
#pragma unroll
      for (int i = 0; i < 16; ++i) {
        int idx4 = tid + 256 * (half * 16 + i);
        int row = idx4 >> 6;                  // 0..127
        int colb = (idx4 & 63) * 8;
        *(uint2*)(smem + row * 512 + (colb ^ ((row & 7) << 4))) =
            make_uint2(cvtpk(tmp[i].x, tmp[i].y), cvtpk(tmp[i].z, tmp[i].w));
      }
    }
  }
  __syncthreads();

  const int abase0 = l15 * 512;          // B-frag lane row base (row = rf*16+l15)
  const int asw    = (l15 & 7) << 4;     // swizzle (row&7 == l15&7 for all frags)
  const int koff0  = lhi * 16;           // byte sub-offset within 64B k-step
  const short* wb1 = W1p + wv * 4 * 4096 + lane * 8;   // packed wave base
  const short* wb2 = W2p + wv * 4 * 4096 + lane * 8;

  // bias per (ef, j): e = wv*64 + ef*16 + lhi*4 + j
  float4 b1v[4], b2v[4];
#pragma unroll
  for (int ef = 0; ef < 4; ++ef) {
    b1v[ef] = *(const float4*)(b1 + wv * 64 + ef * 16 + lhi * 4);
    b2v[ef] = *(const float4*)(b2 + wv * 64 + ef * 16 + lhi * 4);
  }

  const f32x4 z4 = {0.f, 0.f, 0.f, 0.f};
  f32x4 acc[4][8];

  // ================= GEMM1: H = relu(X*W1 + b1) =================
#pragma unroll
  for (int ef = 0; ef < 4; ++ef)
#pragma unroll
    for (int rf = 0; rf < 8; ++rf) acc[ef][rf] = z4;
  gemm_kloop(wb1, smem, abase0, asw, koff0, acc);
  __syncthreads();   // all waves done reading X
#pragma unroll
  for (int ef = 0; ef < 4; ++ef) {
    const int eb = (wv * 64 + ef * 16 + lhi * 4) * 2;
#pragma unroll
    for (int rf = 0; rf < 8; ++rf) {
      float a0 = fmaxf(acc[ef][rf][0] + b1v[ef].x, 0.0f);
      float a1 = fmaxf(acc[ef][rf][1] + b1v[ef].y, 0.0f);
      float a2 = fmaxf(acc[ef][rf][2] + b1v[ef].z, 0.0f);
      float a3 = fmaxf(acc[ef][rf][3] + b1v[ef].w, 0.0f);
      *(uint2*)(smem + rf * 8192 + abase0 + (eb ^ asw)) =
          make_uint2(cvtpk(a0, a1), cvtpk(a2, a3));
    }
  }
  __syncthreads();

  // ================= GEMM2: P = H*W2 + b2 (+ f32 norm partials) =================
#pragma unroll
  for (int ef = 0; ef < 4; ++ef)
#pragma unroll
    for (int rf = 0; rf < 8; ++rf) acc[ef][rf] = z4;
  gemm_kloop(wb2, smem, abase0, asw, koff0, acc);
  __syncthreads();   // all waves done reading H

  float pn[8] = {0.f, 0.f, 0.f, 0.f, 0.f, 0.f, 0.f, 0.f};
#pragma unroll
  for (int ef = 0; ef < 4; ++ef) {
    const int eb = (wv * 64 + ef * 16 + lhi * 4) * 2;
#pragma unroll
    for (int rf = 0; rf < 8; ++rf) {
      float a0 = acc[ef][rf][0] + b2v[ef].x;
      float a1 = acc[ef][rf][1] + b2v[ef].y;
      float a2 = acc[ef][rf][2] + b2v[ef].z;
      float a3 = acc[ef][rf][3] + b2v[ef].w;
      pn[rf] += a0 * a0 + a1 * a1 + a2 * a2 + a3 * a3;
      *(uint2*)(smem + rf * 8192 + abase0 + (eb ^ asw)) =
          make_uint2(cvtpk(a0, a1), cvtpk(a2, a3));
    }
  }
#pragma unroll
  for (int rf = 0; rf < 8; ++rf) {
    pn[rf] += __shfl_xor(pn[rf], 16);
    pn[rf] += __shfl_xor(pn[rf], 32);
  }
  __syncthreads();   // P staged

  // ========= qr GEMM (M-split): qr[k][m] = sum_d Pq[k][d]*Pr[m][d] =========
  f32x4 accC[4];
#pragma unroll
  for (int n = 0; n < 4; ++n) accC[n] = z4;
#pragma unroll
  for (int ks = 0; ks < 8; ++ks) {
    const int ko = (ks * 64 + koff0) ^ asw;
    s16x8 aQ = *(const s16x8*)(smem + wv * 8192 + abase0 + ko);
#pragma unroll
    for (int n = 0; n < 4; ++n) {
      s16x8 bR = *(const s16x8*)(smem + 32768 + n * 8192 + abase0 + ko);
      accC[n] = MFMA16(aQ, bR, accC[n]);
    }
  }
  __syncthreads();   // P reads done -> tile head free for norm exchange

  if (lhi == 0) {
#pragma unroll
    for (int rf = 0; rf < 8; ++rf) nbuf[wv * 128 + rf * 16 + l15] = pn[rf];
  }
  __syncthreads();

  f32x4 nq = z4;
#pragma unroll
  for (int w = 0; w < 4; ++w)
    nq += *(const f32x4*)(nbuf + w * 128 + wv * 16 + lhi * 4);
  float nR[4];
#pragma unroll
  for (int n = 0; n < 4; ++n) {
    float s = 0.0f;
#pragma unroll
    for (int w = 0; w < 4; ++w) s += nbuf[w * 128 + 64 + n * 16 + l15];
    nR[n] = s;
  }
  __syncthreads();   // nbuf reads done -> head region free for C tile

  // ---------- C tile in LDS: C = sqrt(max(q2 + r2 - 2*qr, 0)) ----------
#pragma unroll
  for (int n = 0; n < 4; ++n)
#pragma unroll
    for (int j = 0; j < 4; ++j) {
      int k = wv * 16 + lhi * 4 + j;
      int m = n * 16 + l15;
      float d2 = nq[j] + nR[n] - 2.0f * accC[n][j];
      tile[k * 65 + m] = sqrtf(fmaxf(d2, 0.0f));
    }
  if (tid < 64) w_arr[tid] = __logf(fmaxf(mr, 1e-8f));
  __syncthreads();

  // C -> global (coalesced, write-only; never re-read)
  {
    float* Cb = out + OFF_C + (size_t)b * 4096;
#pragma unroll
    for (int i = 0; i < 16; ++i) {
      int idx = tid + 256 * i;
      Cb[idx] = tile[(idx >> 6) * 65 + (idx & 63)];
    }
  }

  // ================= Sinkhorn (R2 register-cached solver) =================
  const int rk = tid >> 2;
  const int g  = tid & 3;
  const int e0 = g * 16;

  float cn[16], cc[16];
#pragma unroll
  for (int i = 0; i < 16; ++i) {
    cn[i] = tile[rk * 65 + e0 + i] * -20.0f;
    cc[i] = tile[(e0 + i) * 65 + rk] * -20.0f;
  }

  for (int it = 0; it < 20; ++it) {
    {
      float v[16];
#pragma unroll
      for (int i = 0; i < 16; ++i) v[i] = cn[i] + w_arr[e0 + i];
      float mx = v[0];
#pragma unroll
      for (int i = 1; i < 16; ++i) mx = fmaxf(mx, v[i]);
      float s = 0.0f;
#pragma unroll
      for (int i = 0; i < 16; ++i) s += __expf(v[i] - mx);
#pragma unroll
      for (int d = 1; d < 4; d <<= 1) {
        float mo = __shfl_xor(mx, d), so = __shfl_xor(s, d);
        float nm = fmaxf(mx, mo);
        s = s * __expf(mx - nm) + so * __expf(mo - nm);
        mx = nm;
      }
      if (g == 0) u_arr[rk] = -(mx + __logf(s));
    }
    __syncthreads();
    {
      float v[16];
#pragma unroll
      for (int i = 0; i < 16; ++i) v[i] = cc[i] + u_arr[e0 + i];
      float mx = v[0];
#pragma unroll
      for (int i = 1; i < 16; ++i) mx = fmaxf(mx, v[i]);
      float s = 0.0f;
#pragma unroll
      for (int i = 0; i < 16; ++i) s += __expf(v[i] - mx);
#pragma unroll
      for (int d = 1; d < 4; d <<= 1) {
        float mo = __shfl_xor(mx, d), so = __shfl_xor(s, d);
        float nm = fmaxf(mx, mo);
        s = s * __expf(mx - nm) + so * __expf(mo - nm);
        mx = nm;
      }
      if (g == 0) w_arr[rk] = -(mx + __logf(s));
    }
    __syncthreads();
  }

  // ---------------- T = exp(cn + u + w), then MESH x3 ----------------
  float t[16];
  {
    float uk = u_arr[rk];
#pragma unroll
    for (int i = 0; i < 16; ++i) t[i] = __expf(cn[i] + uk + w_arr[e0 + i]);
  }
  for (int it = 0; it < 3; ++it) {
    if (it > 0) {
      __syncthreads();
#pragma unroll
      for (int i = 0; i < 16; ++i) t[i] = tile[rk * 65 + e0 + i];
    }
    // row: square + normalize by rowsum
    float s = 0.0f;
#pragma unroll
    for (int i = 0; i < 16; ++i) { t[i] *= t[i]; s += t[i]; }
    s += __shfl_xor(s, 1); s += __shfl_xor(s, 2);
    float inv = 1.0f / (s + 1e-8f);
#pragma unroll
    for (int i = 0; i < 16; ++i) tile[rk * 65 + e0 + i] = t[i] * inv;
    __syncthreads();
    // col: normalize by colsum
    float tc[16]; float cs = 0.0f;
#pragma unroll
    for (int i = 0; i < 16; ++i) { tc[i] = tile[(e0 + i) * 65 + rk]; cs += tc[i]; }
    cs += __shfl_xor(cs, 1); cs += __shfl_xor(cs, 2);
    inv = 1.0f / (cs + 1e-8f);
#pragma unroll
    for (int i = 0; i < 16; ++i) tile[(e0 + i) * 65 + rk] = tc[i] * inv;
  }
  __syncthreads();

  // ---------------- transport cost + similarity + T store ----------------
  {
    float part = 0.0f;
#pragma unroll
    for (int i = 0; i < 16; ++i)
      part += tile[rk * 65 + e0 + i] * (cn[i] * -0.05f);
#pragma unroll
    for (int d = 1; d < 64; d <<= 1) part += __shfl_xor(part, d);
    if (lane == 0) red[wv] = part;
  }
  __syncthreads();
  if (tid == 0) {
    float tcv = red[0] + red[1] + red[2] + red[3];
    out[OFF_TC + b] = tcv;
    out[b] = 1.0f / (1.0f + __expf(tcv));
  }
  {
    float* Tout = out + OFF_T + (size_t)b * 4096;
#pragma unroll
    for (int i = 0; i < 16; ++i) {
      int idx = tid + 256 * i;
      Tout[idx] = tile[(idx >> 6) * 65 + (idx & 63)];
    }
  }
}

extern "C" void kernel_launch(void* const* d_in, const int* in_sizes, int n_in,
                              void* d_out, int out_size, void* d_ws, size_t ws_size,
                              hipStream_t stream) {
  const float* slots_q = (const float*)d_in[0];
  const float* slots_r = (const float*)d_in[1];
  // d_in[2] = mask_q: cancels out of T/T_hard/C/cost (row-rescaling invariance).
  const float* mask_r = (const float*)d_in[3];
  const float* W1 = (const float*)d_in[4];
  const float* b1 = (const float*)d_in[5];
  const float* W2 = (const float*)d_in[6];
  const float* b2 = (const float*)d_in[7];

  short* W1p = (short*)d_ws;            // fragment-major packed bf16 weights
  short* W2p = W1p + 65536;

  prep_w_kernel<<<256, 256, 0, stream>>>(W1, W2, W1p, W2p);
  sinkhorn_fused<<<2048, 256, 0, stream>>>(slots_q, slots_r, W1p, W2p, b1, b2,
                                           mask_r, (float*)d_out);
}

// Round 13
// 251.211 us; speedup vs baseline: 1.0020x; 1.0020x over previous
//
#include <hip/hip_runtime.h>

// SinkhornOT — round 13: REVERT to R7 split (best verified, 244.6us) + one
// validated micro-win: C epilogue staged through LDS tile (R12-validated code
// path) -> coalesced 1KB/wave C stores instead of scattered dword writes.
// B=2048, K=M=64, D=256, eps=0.05, 20 sinkhorn iters, 3 MESH iters.

typedef __attribute__((ext_vector_type(8))) short s16x8;
typedef __attribute__((ext_vector_type(4))) float f32x4;

#define OFF_T  2048
#define OFF_C  (2048 + 2048 * 4096)
#define OFF_TC (2048 + 2 * 2048 * 4096)

__device__ __forceinline__ unsigned short f2bf(float x) {  // RNE f32->bf16
  unsigned u = __builtin_bit_cast(unsigned, x);
  u += 0x7fffu + ((u >> 16) & 1u);
  return (unsigned short)(u >> 16);
}
__device__ __forceinline__ unsigned cvtpk(float lo, float hi) {
  unsigned r;
  asm("v_cvt_pk_bf16_f32 %0, %1, %2" : "=v"(r) : "v"(lo), "v"(hi));
  return r;
}

#define MFMA16(a, b, c) __builtin_amdgcn_mfma_f32_16x16x32_bf16((a), (b), (c), 0, 0, 0)

// Pack W (f32 [k][col]) into fragment-major bf16 (1KiB contiguous per frag:
// frag (cf=col>>4, ks=k>>5) at cf*4096+ks*512, lane=((k>>3)&3)*16+(col&15),
// byte ii=k&7). Serves as the swapped-GEMM A-operand.
__global__ void __launch_bounds__(256)
prep_w_kernel(const float* __restrict__ W1, const float* __restrict__ W2,
              short* __restrict__ W1p, short* __restrict__ W2p) {
  int i = blockIdx.x * 256 + threadIdx.x;   // 65536 threads exactly
  int k = i >> 8, col = i & 255;
  int p = (col >> 4) * 4096 + (k >> 5) * 512 +
          (((k >> 3) & 3) * 16 + (col & 15)) * 8 + (k & 7);
  W1p[p] = (short)f2bf(W1[i]);
  W2p[p] = (short)f2bf(W2[i]);
}

// K-loop, operand-swapped: acc[nf][rf] holds D[e][r]. A = packed W frag
// (depth-4 register ring), B = X/H row frag from LDS.
__device__ __forceinline__ void gemm_kloop(const short* __restrict__ wb,
                                           const char* sm, int abase0, int asw,
                                           int koff0, f32x4 (&acc)[4][8]) {
  s16x8 bw[4][4];
#pragma unroll
  for (int p = 0; p < 4; ++p)
#pragma unroll
    for (int nf = 0; nf < 4; ++nf)
      bw[p][nf] = *(const s16x8*)(wb + nf * 4096 + p * 512);
#pragma unroll
  for (int ks = 0; ks < 8; ++ks) {
    const int ko = (ks * 64 + koff0) ^ asw;
    s16x8 af[8];
#pragma unroll
    for (int rf = 0; rf < 8; ++rf)
      af[rf] = *(const s16x8*)(sm + rf * 8192 + abase0 + ko);
#pragma unroll
    for (int rf = 0; rf < 8; ++rf)
#pragma unroll
      for (int nf = 0; nf < 4; ++nf)
        acc[nf][rf] = MFMA16(bw[ks & 3][nf], af[rf], acc[nf][rf]);
    if (ks < 4) {
#pragma unroll
      for (int nf = 0; nf < 4; ++nf)
        bw[ks & 3][nf] = *(const s16x8*)(wb + nf * 4096 + (ks + 4) * 512);
    }
  }
}

// ======================= Kernel A: projections + cdist =======================
__global__ void __launch_bounds__(256, 2)
proj_cost_kernel(const float* __restrict__ slots_q, const float* __restrict__ slots_r,
                 const short* __restrict__ W1p, const short* __restrict__ W2p,
                 const float* __restrict__ b1, const float* __restrict__ b2,
                 float* __restrict__ out) {
  // [128 rows][512 B] swizzled bf16 tile: X -> H -> P (rows 0-63 Q, 64-127 R).
  // Head reused as norm-partials [4][128] f32 (post-qr), then C tile [64][65].
  __shared__ char smem[65536];
  float* nbuf = (float*)smem;
  float* tile = (float*)smem;   // [64][65] f32 (16640 B)

  const int b    = blockIdx.x;
  const int tid  = threadIdx.x;
  const int wv   = tid >> 6;
  const int lane = tid & 63;
  const int l15  = lane & 15;
  const int lhi  = lane >> 4;

  // ---------- stage X: 16 loads in flight, then convert+write (x2) ----------
  {
    const float* sq = slots_q + (size_t)b * 16384;
    const float* sr = slots_r + (size_t)b * 16384;
#pragma unroll
    for (int half = 0; half < 2; ++half) {
      float4 tmp[16];
#pragma unroll
      for (int i = 0; i < 16; ++i) {
        int idx4 = tid + 256 * (half * 16 + i);
        tmp[i] = (half == 0) ? *(const float4*)(sq + idx4 * 4)
                             : *(const float4*)(sr + (idx4 - 4096) * 4);
      }
#pragma unroll
      for (int i = 0; i < 16; ++i) {
        int idx4 = tid + 256 * (half * 16 + i);
        int row = idx4 >> 6;                  // 0..127
        int colb = (idx4 & 63) * 8;
        *(uint2*)(smem + row * 512 + (colb ^ ((row & 7) << 4))) =
            make_uint2(cvtpk(tmp[i].x, tmp[i].y), cvtpk(tmp[i].z, tmp[i].w));
      }
    }
  }
  __syncthreads();

  const int abase0 = l15 * 512;          // B-frag lane row base (row = rf*16+l15)
  const int asw    = (l15 & 7) << 4;     // swizzle (row&7 == l15&7 for all frags)
  const int koff0  = lhi * 16;           // byte sub-offset within 64B k-step
  const short* wb1 = W1p + wv * 4 * 4096 + lane * 8;   // packed wave base
  const short* wb2 = W2p + wv * 4 * 4096 + lane * 8;

  // bias per (ef, j): e = wv*64 + ef*16 + lhi*4 + j
  float4 b1v[4], b2v[4];
#pragma unroll
  for (int ef = 0; ef < 4; ++ef) {
    b1v[ef] = *(const float4*)(b1 + wv * 64 + ef * 16 + lhi * 4);
    b2v[ef] = *(const float4*)(b2 + wv * 64 + ef * 16 + lhi * 4);
  }

  const f32x4 z4 = {0.f, 0.f, 0.f, 0.f};
  f32x4 acc[4][8];

  // ================= GEMM1: H = relu(X*W1 + b1) =================
#pragma unroll
  for (int ef = 0; ef < 4; ++ef)
#pragma unroll
    for (int rf = 0; rf < 8; ++rf) acc[ef][rf] = z4;
  gemm_kloop(wb1, smem, abase0, asw, koff0, acc);
  __syncthreads();   // all waves done reading X
  // write H: per (ef,rf) lane holds 4 consecutive e for row rf*16+l15 -> b64
#pragma unroll
  for (int ef = 0; ef < 4; ++ef) {
    const int eb = (wv * 64 + ef * 16 + lhi * 4) * 2;
#pragma unroll
    for (int rf = 0; rf < 8; ++rf) {
      float a0 = fmaxf(acc[ef][rf][0] + b1v[ef].x, 0.0f);
      float a1 = fmaxf(acc[ef][rf][1] + b1v[ef].y, 0.0f);
      float a2 = fmaxf(acc[ef][rf][2] + b1v[ef].z, 0.0f);
      float a3 = fmaxf(acc[ef][rf][3] + b1v[ef].w, 0.0f);
      *(uint2*)(smem + rf * 8192 + abase0 + (eb ^ asw)) =
          make_uint2(cvtpk(a0, a1), cvtpk(a2, a3));
    }
  }
  __syncthreads();

  // ================= GEMM2: P = H*W2 + b2 (+ f32 norm partials) =================
#pragma unroll
  for (int ef = 0; ef < 4; ++ef)
#pragma unroll
    for (int rf = 0; rf < 8; ++rf) acc[ef][rf] = z4;
  gemm_kloop(wb2, smem, abase0, asw, koff0, acc);
  __syncthreads();   // all waves done reading H

  float pn[8] = {0.f, 0.f, 0.f, 0.f, 0.f, 0.f, 0.f, 0.f};
#pragma unroll
  for (int ef = 0; ef < 4; ++ef) {
    const int eb = (wv * 64 + ef * 16 + lhi * 4) * 2;
#pragma unroll
    for (int rf = 0; rf < 8; ++rf) {
      float a0 = acc[ef][rf][0] + b2v[ef].x;
      float a1 = acc[ef][rf][1] + b2v[ef].y;
      float a2 = acc[ef][rf][2] + b2v[ef].z;
      float a3 = acc[ef][rf][3] + b2v[ef].w;
      pn[rf] += a0 * a0 + a1 * a1 + a2 * a2 + a3 * a3;
      *(uint2*)(smem + rf * 8192 + abase0 + (eb ^ asw)) =
          make_uint2(cvtpk(a0, a1), cvtpk(a2, a3));
    }
  }
  // reduce norm partials over the 4 lanes sharing l15 (lhi = 0..3)
#pragma unroll
  for (int rf = 0; rf < 8; ++rf) {
    pn[rf] += __shfl_xor(pn[rf], 16);
    pn[rf] += __shfl_xor(pn[rf], 32);
  }
  __syncthreads();   // P staged

  // ========= qr GEMM (M-split): qr[k][m] = sum_d Pq[k][d]*Pr[m][d] =========
  f32x4 accC[4];
#pragma unroll
  for (int n = 0; n < 4; ++n) accC[n] = z4;
#pragma unroll
  for (int ks = 0; ks < 8; ++ks) {
    const int ko = (ks * 64 + koff0) ^ asw;
    s16x8 aQ = *(const s16x8*)(smem + wv * 8192 + abase0 + ko);
#pragma unroll
    for (int n = 0; n < 4; ++n) {
      s16x8 bR = *(const s16x8*)(smem + 32768 + n * 8192 + abase0 + ko);
      accC[n] = MFMA16(aQ, bR, accC[n]);
    }
  }
  __syncthreads();   // P reads done -> tile head free for norm exchange

  // nbuf[wv*128 + row] = this wave's 64-col partial for row
  if (lhi == 0) {
#pragma unroll
    for (int rf = 0; rf < 8; ++rf) nbuf[wv * 128 + rf * 16 + l15] = pn[rf];
  }
  __syncthreads();

  f32x4 nq = z4;
#pragma unroll
  for (int w = 0; w < 4; ++w)
    nq += *(const f32x4*)(nbuf + w * 128 + wv * 16 + lhi * 4);
  float nR[4];
#pragma unroll
  for (int n = 0; n < 4; ++n) {
    float s = 0.0f;
#pragma unroll
    for (int w = 0; w < 4; ++w) s += nbuf[w * 128 + 64 + n * 16 + l15];
    nR[n] = s;
  }
  __syncthreads();   // nbuf reads done -> head region free for C tile

  // ---------- C tile in LDS, then coalesced global store (R12-validated) ----------
#pragma unroll
  for (int n = 0; n < 4; ++n)
#pragma unroll
    for (int j = 0; j < 4; ++j) {
      int k = wv * 16 + lhi * 4 + j;
      int m = n * 16 + l15;
      float d2 = nq[j] + nR[n] - 2.0f * accC[n][j];
      tile[k * 65 + m] = sqrtf(fmaxf(d2, 0.0f));
    }
  __syncthreads();
  {
    float* Cb = out + OFF_C + (size_t)b * 4096;
#pragma unroll
    for (int i = 0; i < 16; ++i) {
      int idx = tid + 256 * i;
      Cb[idx] = tile[(idx >> 6) * 65 + (idx & 63)];
    }
  }
}

// ======================= Kernel B: Sinkhorn + MESH + outputs (R7 proven) =======================
__global__ void __launch_bounds__(256, 4)
sinkhorn_solve(const float* __restrict__ mask_r, float* __restrict__ out) {
  __shared__ float tile[64 * 65];   // C load staging, then T tile for MESH
  __shared__ float u_arr[64], w_arr[64], red[4];

  const int b    = blockIdx.x;
  const int tid  = threadIdx.x;
  const int wv   = tid >> 6;
  const int lane = tid & 63;
  const int rk   = tid >> 2;    // row (or col) this thread group owns
  const int g    = tid & 3;     // 4-lane split of the 64-wide reduction
  const int e0   = g * 16;

  const float* Cb = out + OFF_C + (size_t)b * 4096;

  // load C coalesced -> LDS tile
#pragma unroll
  for (int i = 0; i < 16; ++i) {
    int idx = tid + 256 * i;
    tile[(idx >> 6) * 65 + (idx & 63)] = Cb[idx];
  }
  if (tid < 64) w_arr[tid] = __logf(fmaxf(mask_r[(size_t)b * 64 + tid], 1e-8f));
  __syncthreads();

  // C slices into registers: cn = row slice * (-1/eps), cc = col slice * (-1/eps)
  float cn[16], cc[16];
#pragma unroll
  for (int i = 0; i < 16; ++i) {
    cn[i] = tile[rk * 65 + e0 + i] * -20.0f;
    cc[i] = tile[(e0 + i) * 65 + rk] * -20.0f;
  }

  // ---------------- Sinkhorn: u = -lse_m(cn + w); w = -lse_k(cc + u) ----------------
  for (int it = 0; it < 20; ++it) {
    {
      float v[16];
#pragma unroll
      for (int i = 0; i < 16; ++i) v[i] = cn[i] + w_arr[e0 + i];
      float mx = v[0];
#pragma unroll
      for (int i = 1; i < 16; ++i) mx = fmaxf(mx, v[i]);
      float s = 0.0f;
#pragma unroll
      for (int i = 0; i < 16; ++i) s += __expf(v[i] - mx);
#pragma unroll
      for (int d = 1; d < 4; d <<= 1) {
        float mo = __shfl_xor(mx, d), so = __shfl_xor(s, d);
        float nm = fmaxf(mx, mo);
        s = s * __expf(mx - nm) + so * __expf(mo - nm);
        mx = nm;
      }
      if (g == 0) u_arr[rk] = -(mx + __logf(s));
    }
    __syncthreads();
    {
      float v[16];
#pragma unroll
      for (int i = 0; i < 16; ++i) v[i] = cc[i] + u_arr[e0 + i];
      float mx = v[0];
#pragma unroll
      for (int i = 1; i < 16; ++i) mx = fmaxf(mx, v[i]);
      float s = 0.0f;
#pragma unroll
      for (int i = 0; i < 16; ++i) s += __expf(v[i] - mx);
#pragma unroll
      for (int d = 1; d < 4; d <<= 1) {
        float mo = __shfl_xor(mx, d), so = __shfl_xor(s, d);
        float nm = fmaxf(mx, mo);
        s = s * __expf(mx - nm) + so * __expf(mo - nm);
        mx = nm;
      }
      if (g == 0) w_arr[rk] = -(mx + __logf(s));
    }
    __syncthreads();
  }

  // ---------------- T = exp(cn + u + w), then MESH x3 ----------------
  float t[16];
  {
    float uk = u_arr[rk];
#pragma unroll
    for (int i = 0; i < 16; ++i) t[i] = __expf(cn[i] + uk + w_arr[e0 + i]);
  }
  for (int it = 0; it < 3; ++it) {
    if (it > 0) {
      __syncthreads();
#pragma unroll
      for (int i = 0; i < 16; ++i) t[i] = tile[rk * 65 + e0 + i];
    }
    // row: square + normalize by rowsum
    float s = 0.0f;
#pragma unroll
    for (int i = 0; i < 16; ++i) { t[i] *= t[i]; s += t[i]; }
    s += __shfl_xor(s, 1); s += __shfl_xor(s, 2);
    float inv = 1.0f / (s + 1e-8f);
#pragma unroll
    for (int i = 0; i < 16; ++i) tile[rk * 65 + e0 + i] = t[i] * inv;
    __syncthreads();
    // col: normalize by colsum
    float tc[16]; float cs = 0.0f;
#pragma unroll
    for (int i = 0; i < 16; ++i) { tc[i] = tile[(e0 + i) * 65 + rk]; cs += tc[i]; }
    cs += __shfl_xor(cs, 1); cs += __shfl_xor(cs, 2);
    inv = 1.0f / (cs + 1e-8f);
#pragma unroll
    for (int i = 0; i < 16; ++i) tile[(e0 + i) * 65 + rk] = tc[i] * inv;
  }
  __syncthreads();

  // ---------------- transport cost + similarity + T store ----------------
  {
    float part = 0.0f;
#pragma unroll
    for (int i = 0; i < 16; ++i)
      part += tile[rk * 65 + e0 + i] * (cn[i] * -0.05f);
#pragma unroll
    for (int d = 1; d < 64; d <<= 1) part += __shfl_xor(part, d);
    if (lane == 0) red[wv] = part;
  }
  __syncthreads();
  if (tid == 0) {
    float tc = red[0] + red[1] + red[2] + red[3];
    out[OFF_TC + b] = tc;
    out[b] = 1.0f / (1.0f + __expf(tc));
  }
  {
    float* Tout = out + OFF_T + (size_t)b * 4096;
#pragma unroll
    for (int i = 0; i < 16; ++i) {
      int idx = tid + 256 * i;
      Tout[idx] = tile[(idx >> 6) * 65 + (idx & 63)];
    }
  }
}

extern "C" void kernel_launch(void* const* d_in, const int* in_sizes, int n_in,
                              void* d_out, int out_size, void* d_ws, size_t ws_size,
                              hipStream_t stream) {
  const float* slots_q = (const float*)d_in[0];
  const float* slots_r = (const float*)d_in[1];
  // d_in[2] = mask_q: cancels out of T/T_hard/C/cost (row-rescaling invariance).
  const float* mask_r = (const float*)d_in[3];
  const float* W1 = (const float*)d_in[4];
  const float* b1 = (const float*)d_in[5];
  const float* W2 = (const float*)d_in[6];
  const float* b2 = (const float*)d_in[7];

  short* W1p = (short*)d_ws;            // fragment-major packed bf16 weights
  short* W2p = W1p + 65536;

  prep_w_kernel<<<256, 256, 0, stream>>>(W1, W2, W1p, W2p);
  proj_cost_kernel<<<2048, 256, 0, stream>>>(slots_q, slots_r, W1p, W2p, b1, b2,
                                             (float*)d_out);
  sinkhorn_solve<<<2048, 256, 0, stream>>>(mask_r, (float*)d_out);
}

// Round 14
// 244.666 us; speedup vs baseline: 1.0288x; 1.0268x over previous
//
#include <hip/hip_runtime.h>

// SinkhornOT — FINAL: exact revert to round-7 kernel (best verified, 244.6us;
// reproduced at 245-249 in R11). Depth-4 W register-ring prefetch + two-phase
// batched X staging + operand-swapped MFMA projections + M-split qr + split
// high-occupancy Sinkhorn/MESH solver.
// Session evidence: all tested structural alternatives (occupancy 2x/4x, W
// coalescing, VALU reduction, fusion, batch-loop prefetch, coalesced-C) are
// neutral-to-negative; proj runs at ~391 TF effective = the measured band for
// a 2-barrier MFMA structure at this per-block shape (learn_hip m102).
// B=2048, K=M=64, D=256, eps=0.05, 20 sinkhorn iters, 3 MESH iters.

typedef __attribute__((ext_vector_type(8))) short s16x8;
typedef __attribute__((ext_vector_type(4))) float f32x4;

#define OFF_T  2048
#define OFF_C  (2048 + 2048 * 4096)
#define OFF_TC (2048 + 2 * 2048 * 4096)

__device__ __forceinline__ unsigned short f2bf(float x) {  // RNE f32->bf16
  unsigned u = __builtin_bit_cast(unsigned, x);
  u += 0x7fffu + ((u >> 16) & 1u);
  return (unsigned short)(u >> 16);
}
__device__ __forceinline__ unsigned cvtpk(float lo, float hi) {
  unsigned r;
  asm("v_cvt_pk_bf16_f32 %0, %1, %2" : "=v"(r) : "v"(lo), "v"(hi));
  return r;
}

#define MFMA16(a, b, c) __builtin_amdgcn_mfma_f32_16x16x32_bf16((a), (b), (c), 0, 0, 0)

// Pack W (f32 [k][col]) into fragment-major bf16: fragment (cf=col>>4,
// ks=k>>5) is a contiguous 1KiB burst, 16B/lane, lane=((k>>3)&3)*16+(col&15),
// byte ii=k&7. Serves as the MFMA A-operand for the operand-swapped GEMMs.
__global__ void __launch_bounds__(256)
prep_w_kernel(const float* __restrict__ W1, const float* __restrict__ W2,
              short* __restrict__ W1p, short* __restrict__ W2p) {
  int i = blockIdx.x * 256 + threadIdx.x;   // 65536 threads exactly
  int k = i >> 8, col = i & 255;
  int p = (col >> 4) * 4096 + (k >> 5) * 512 +
          (((k >> 3) & 3) * 16 + (col & 15)) * 8 + (k & 7);
  W1p[p] = (short)f2bf(W1[i]);
  W2p[p] = (short)f2bf(W2[i]);
}

// K-loop, operand-swapped: acc[nf][rf] holds D[e][r]. A = packed W frag
// (depth-4 register ring), B = X/H row frag from LDS.
__device__ __forceinline__ void gemm_kloop(const short* __restrict__ wb,
                                           const char* sm, int abase0, int asw,
                                           int koff0, f32x4 (&acc)[4][8]) {
  s16x8 bw[4][4];                 // 4-deep ring x 4 col-frags
#pragma unroll
  for (int p = 0; p < 4; ++p)
#pragma unroll
    for (int nf = 0; nf < 4; ++nf)
      bw[p][nf] = *(const s16x8*)(wb + nf * 4096 + p * 512);
#pragma unroll
  for (int ks = 0; ks < 8; ++ks) {
    const int ko = (ks * 64 + koff0) ^ asw;
    s16x8 af[8];
#pragma unroll
    for (int rf = 0; rf < 8; ++rf)
      af[rf] = *(const s16x8*)(sm + rf * 8192 + abase0 + ko);
#pragma unroll
    for (int rf = 0; rf < 8; ++rf)
#pragma unroll
      for (int nf = 0; nf < 4; ++nf)
        acc[nf][rf] = MFMA16(bw[ks & 3][nf], af[rf], acc[nf][rf]);
    if (ks < 4) {                 // refill the slot just consumed, +4 ahead
#pragma unroll
      for (int nf = 0; nf < 4; ++nf)
        bw[ks & 3][nf] = *(const s16x8*)(wb + nf * 4096 + (ks + 4) * 512);
    }
  }
}

// ======================= Kernel A: projections + cdist =======================
__global__ void __launch_bounds__(256, 2)
proj_cost_kernel(const float* __restrict__ slots_q, const float* __restrict__ slots_r,
                 const short* __restrict__ W1p, const short* __restrict__ W2p,
                 const float* __restrict__ b1, const float* __restrict__ b2,
                 float* __restrict__ out) {
  // [128 rows][512 B] swizzled bf16 tile: X -> H -> P (rows 0-63 Q, 64-127 R).
  // After qr-GEMM frees it, head reused as norm-partials buffer [4][128] f32.
  __shared__ char smem[65536];
  float* nbuf = (float*)smem;

  const int b    = blockIdx.x;
  const int tid  = threadIdx.x;
  const int wv   = tid >> 6;
  const int lane = tid & 63;
  const int l15  = lane & 15;
  const int lhi  = lane >> 4;

  // ---------- stage X: 16 loads in flight, then convert+write (x2) ----------
  {
    const float* sq = slots_q + (size_t)b * 16384;
    const float* sr = slots_r + (size_t)b * 16384;
#pragma unroll
    for (int half = 0; half < 2; ++half) {
      float4 tmp[16];
#pragma unroll
      for (int i = 0; i < 16; ++i) {
        int idx4 = tid + 256 * (half * 16 + i);
        tmp[i] = (half == 0) ? *(const float4*)(sq + idx4 * 4)
                             : *(const float4*)(sr + (idx4 - 4096) * 4);
      }
#pragma unroll
      for (int i = 0; i < 16; ++i) {
        int idx4 = tid + 256 * (half * 16 + i);
        int row = idx4 >> 6;                  // 0..127
        int colb = (idx4 & 63) * 8;
        *(uint2*)(smem + row * 512 + (colb ^ ((row & 7) << 4))) =
            make_uint2(cvtpk(tmp[i].x, tmp[i].y), cvtpk(tmp[i].z, tmp[i].w));
      }
    }
  }
  __syncthreads();

  const int abase0 = l15 * 512;          // B-frag lane row base (row = rf*16+l15)
  const int asw    = (l15 & 7) << 4;     // swizzle (row&7 == l15&7 for all frags)
  const int koff0  = lhi * 16;           // byte sub-offset within 64B k-step
  const short* wb1 = W1p + wv * 4 * 4096 + lane * 8;   // packed wave base
  const short* wb2 = W2p + wv * 4 * 4096 + lane * 8;

  // bias per (ef, j): e = wv*64 + ef*16 + lhi*4 + j
  float4 b1v[4], b2v[4];
#pragma unroll
  for (int ef = 0; ef < 4; ++ef) {
    b1v[ef] = *(const float4*)(b1 + wv * 64 + ef * 16 + lhi * 4);
    b2v[ef] = *(const float4*)(b2 + wv * 64 + ef * 16 + lhi * 4);
  }

  const f32x4 z4 = {0.f, 0.f, 0.f, 0.f};
  f32x4 acc[4][8];

  // ================= GEMM1: H = relu(X*W1 + b1) =================
#pragma unroll
  for (int ef = 0; ef < 4; ++ef)
#pragma unroll
    for (int rf = 0; rf < 8; ++rf) acc[ef][rf] = z4;
  gemm_kloop(wb1, smem, abase0, asw, koff0, acc);
  __syncthreads();   // all waves done reading X
  // write H: per (ef,rf) lane holds 4 consecutive e for row rf*16+l15 -> b64
#pragma unroll
  for (int ef = 0; ef < 4; ++ef) {
    const int eb = (wv * 64 + ef * 16 + lhi * 4) * 2;
#pragma unroll
    for (int rf = 0; rf < 8; ++rf) {
      float a0 = fmaxf(acc[ef][rf][0] + b1v[ef].x, 0.0f);
      float a1 = fmaxf(acc[ef][rf][1] + b1v[ef].y, 0.0f);
      float a2 = fmaxf(acc[ef][rf][2] + b1v[ef].z, 0.0f);
      float a3 = fmaxf(acc[ef][rf][3] + b1v[ef].w, 0.0f);
      *(uint2*)(smem + rf * 8192 + abase0 + (eb ^ asw)) =
          make_uint2(cvtpk(a0, a1), cvtpk(a2, a3));
    }
  }
  __syncthreads();

  // ================= GEMM2: P = H*W2 + b2 (+ f32 norm partials) =================
#pragma unroll
  for (int ef = 0; ef < 4; ++ef)
#pragma unroll
    for (int rf = 0; rf < 8; ++rf) acc[ef][rf] = z4;
  gemm_kloop(wb2, smem, abase0, asw, koff0, acc);
  __syncthreads();   // all waves done reading H

  float pn[8] = {0.f, 0.f, 0.f, 0.f, 0.f, 0.f, 0.f, 0.f};
#pragma unroll
  for (int ef = 0; ef < 4; ++ef) {
    const int eb = (wv * 64 + ef * 16 + lhi * 4) * 2;
#pragma unroll
    for (int rf = 0; rf < 8; ++rf) {
      float a0 = acc[ef][rf][0] + b2v[ef].x;
      float a1 = acc[ef][rf][1] + b2v[ef].y;
      float a2 = acc[ef][rf][2] + b2v[ef].z;
      float a3 = acc[ef][rf][3] + b2v[ef].w;
      pn[rf] += a0 * a0 + a1 * a1 + a2 * a2 + a3 * a3;
      *(uint2*)(smem + rf * 8192 + abase0 + (eb ^ asw)) =
          make_uint2(cvtpk(a0, a1), cvtpk(a2, a3));
    }
  }
  // reduce norm partials over the 4 lanes sharing l15 (lhi = 0..3)
#pragma unroll
  for (int rf = 0; rf < 8; ++rf) {
    pn[rf] += __shfl_xor(pn[rf], 16);
    pn[rf] += __shfl_xor(pn[rf], 32);
  }
  __syncthreads();   // P staged

  // ========= qr GEMM (M-split): qr[k][m] = sum_d Pq[k][d]*Pr[m][d] =========
  f32x4 accC[4];
#pragma unroll
  for (int n = 0; n < 4; ++n) accC[n] = z4;
#pragma unroll
  for (int ks = 0; ks < 8; ++ks) {
    const int ko = (ks * 64 + koff0) ^ asw;
    s16x8 aQ = *(const s16x8*)(smem + wv * 8192 + abase0 + ko);
#pragma unroll
    for (int n = 0; n < 4; ++n) {
      s16x8 bR = *(const s16x8*)(smem + 32768 + n * 8192 + abase0 + ko);
      accC[n] = MFMA16(aQ, bR, accC[n]);
    }
  }
  __syncthreads();   // P reads done -> tile region free for norm exchange

  // nbuf[wv*128 + row] = this wave's 64-col partial for row
  if (lhi == 0) {
#pragma unroll
    for (int rf = 0; rf < 8; ++rf) nbuf[wv * 128 + rf * 16 + l15] = pn[rf];
  }
  __syncthreads();

  f32x4 nq = z4;
#pragma unroll
  for (int w = 0; w < 4; ++w)
    nq += *(const f32x4*)(nbuf + w * 128 + wv * 16 + lhi * 4);
  float nR[4];
#pragma unroll
  for (int n = 0; n < 4; ++n) {
    float s = 0.0f;
#pragma unroll
    for (int w = 0; w < 4; ++w) s += nbuf[w * 128 + 64 + n * 16 + l15];
    nR[n] = s;
  }

  // C = sqrt(max(q2 + r2 - 2*qr, 0)) -> direct global store
  float* Cb = out + OFF_C + (size_t)b * 4096;
#pragma unroll
  for (int n = 0; n < 4; ++n)
#pragma unroll
    for (int j = 0; j < 4; ++j) {
      float d2 = nq[j] + nR[n] - 2.0f * accC[n][j];
      Cb[(wv * 16 + lhi * 4 + j) * 64 + n * 16 + l15] = sqrtf(fmaxf(d2, 0.0f));
    }
}

// ======================= Kernel B: Sinkhorn + MESH + outputs =======================
__global__ void __launch_bounds__(256, 4)
sinkhorn_solve(const float* __restrict__ mask_r, float* __restrict__ out) {
  __shared__ float tile[64 * 65];   // C load staging, then T tile for MESH
  __shared__ float u_arr[64], w_arr[64], red[4];

  const int b    = blockIdx.x;
  const int tid  = threadIdx.x;
  const int wv   = tid >> 6;
  const int lane = tid & 63;
  const int rk   = tid >> 2;    // row (or col) this thread group owns
  const int g    = tid & 3;     // 4-lane split of the 64-wide reduction
  const int e0   = g * 16;

  const float* Cb = out + OFF_C + (size_t)b * 4096;

  // load C coalesced -> LDS tile
#pragma unroll
  for (int i = 0; i < 16; ++i) {
    int idx = tid + 256 * i;
    tile[(idx >> 6) * 65 + (idx & 63)] = Cb[idx];
  }
  if (tid < 64) w_arr[tid] = __logf(fmaxf(mask_r[(size_t)b * 64 + tid], 1e-8f));
  __syncthreads();

  // C slices into registers: cn = row slice * (-1/eps), cc = col slice * (-1/eps)
  float cn[16], cc[16];
#pragma unroll
  for (int i = 0; i < 16; ++i) {
    cn[i] = tile[rk * 65 + e0 + i] * -20.0f;
    cc[i] = tile[(e0 + i) * 65 + rk] * -20.0f;
  }

  // ---------------- Sinkhorn: u = -lse_m(cn + w); w = -lse_k(cc + u) ----------------
  for (int it = 0; it < 20; ++it) {
    {
      float v[16];
#pragma unroll
      for (int i = 0; i < 16; ++i) v[i] = cn[i] + w_arr[e0 + i];
      float mx = v[0];
#pragma unroll
      for (int i = 1; i < 16; ++i) mx = fmaxf(mx, v[i]);
      float s = 0.0f;
#pragma unroll
      for (int i = 0; i < 16; ++i) s += __expf(v[i] - mx);
#pragma unroll
      for (int d = 1; d < 4; d <<= 1) {
        float mo = __shfl_xor(mx, d), so = __shfl_xor(s, d);
        float nm = fmaxf(mx, mo);
        s = s * __expf(mx - nm) + so * __expf(mo - nm);
        mx = nm;
      }
      if (g == 0) u_arr[rk] = -(mx + __logf(s));
    }
    __syncthreads();
    {
      float v[16];
#pragma unroll
      for (int i = 0; i < 16; ++i) v[i] = cc[i] + u_arr[e0 + i];
      float mx = v[0];
#pragma unroll
      for (int i = 1; i < 16; ++i) mx = fmaxf(mx, v[i]);
      float s = 0.0f;
#pragma unroll
      for (int i = 0; i < 16; ++i) s += __expf(v[i] - mx);
#pragma unroll
      for (int d = 1; d < 4; d <<= 1) {
        float mo = __shfl_xor(mx, d), so = __shfl_xor(s, d);
        float nm = fmaxf(mx, mo);
        s = s * __expf(mx - nm) + so * __expf(mo - nm);
        mx = nm;
      }
      if (g == 0) w_arr[rk] = -(mx + __logf(s));
    }
    __syncthreads();
  }

  // ---------------- T = exp(cn + u + w), then MESH x3 ----------------
  float t[16];
  {
    float uk = u_arr[rk];
#pragma unroll
    for (int i = 0; i < 16; ++i) t[i] = __expf(cn[i] + uk + w_arr[e0 + i]);
  }
  for (int it = 0; it < 3; ++it) {
    if (it > 0) {
      __syncthreads();
#pragma unroll
      for (int i = 0; i < 16; ++i) t[i] = tile[rk * 65 + e0 + i];
    }
    // row: square + normalize by rowsum
    float s = 0.0f;
#pragma unroll
    for (int i = 0; i < 16; ++i) { t[i] *= t[i]; s += t[i]; }
    s += __shfl_xor(s, 1); s += __shfl_xor(s, 2);
    float inv = 1.0f / (s + 1e-8f);
#pragma unroll
    for (int i = 0; i < 16; ++i) tile[rk * 65 + e0 + i] = t[i] * inv;
    __syncthreads();
    // col: normalize by colsum
    float tc[16]; float cs = 0.0f;
#pragma unroll
    for (int i = 0; i < 16; ++i) { tc[i] = tile[(e0 + i) * 65 + rk]; cs += tc[i]; }
    cs += __shfl_xor(cs, 1); cs += __shfl_xor(cs, 2);
    inv = 1.0f / (cs + 1e-8f);
#pragma unroll
    for (int i = 0; i < 16; ++i) tile[(e0 + i) * 65 + rk] = tc[i] * inv;
  }
  __syncthreads();

  // ---------------- transport cost + similarity + T store ----------------
  {
    float part = 0.0f;
#pragma unroll
    for (int i = 0; i < 16; ++i)
      part += tile[rk * 65 + e0 + i] * (cn[i] * -0.05f);
#pragma unroll
    for (int d = 1; d < 64; d <<= 1) part += __shfl_xor(part, d);
    if (lane == 0) red[wv] = part;
  }
  __syncthreads();
  if (tid == 0) {
    float tc = red[0] + red[1] + red[2] + red[3];
    out[OFF_TC + b] = tc;
    out[b] = 1.0f / (1.0f + __expf(tc));
  }
  {
    float* Tout = out + OFF_T + (size_t)b * 4096;
#pragma unroll
    for (int i = 0; i < 16; ++i) {
      int idx = tid + 256 * i;
      Tout[idx] = tile[(idx >> 6) * 65 + (idx & 63)];
    }
  }
}

extern "C" void kernel_launch(void* const* d_in, const int* in_sizes, int n_in,
                              void* d_out, int out_size, void* d_ws, size_t ws_size,
                              hipStream_t stream) {
  const float* slots_q = (const float*)d_in[0];
  const float* slots_r = (const float*)d_in[1];
  // d_in[2] = mask_q: cancels out of T/T_hard/C/cost (row-rescaling invariance).
  const float* mask_r = (const float*)d_in[3];
  const float* W1 = (const float*)d_in[4];
  const float* b1 = (const float*)d_in[5];
  const float* W2 = (const float*)d_in[6];
  const float* b2 = (const float*)d_in[7];

  short* W1p = (short*)d_ws;            // fragment-major packed bf16 weights
  short* W2p = W1p + 65536;

  prep_w_kernel<<<256, 256, 0, stream>>>(W1, W2, W1p, W2p);
  proj_cost_kernel<<<2048, 256, 0, stream>>>(slots_q, slots_r, W1p, W2p, b1, b2,
                                             (float*)d_out);
  sinkhorn_solve<<<2048, 256, 0, stream>>>(mask_r, (float*)d_out);
}